// Round 13
// baseline (115.139 us; speedup 1.0000x reference)
//
#include <hip/hip_runtime.h>

#define HW   4096
#define Hh   64
#define Ww   64
#define NB   27
#define EPSBN 1e-5f

typedef _Float16 f16x8 __attribute__((ext_vector_type(8)));
typedef _Float16 f16x4 __attribute__((ext_vector_type(4)));
typedef _Float16 f16x2 __attribute__((ext_vector_type(2)));
typedef float    f32x4 __attribute__((ext_vector_type(4)));

// async global->LDS, 16B per lane; LDS dest = wave-uniform base + lane*16
__device__ __forceinline__ void gld_lds16(const void* g, void* l) {
    __builtin_amdgcn_global_load_lds(
        (const __attribute__((address_space(1))) unsigned int*)g,
        (__attribute__((address_space(3))) unsigned int*)l, 16, 0, 0);
}

// ---------------------------------------------------------------------------
// prep: weights f32 -> f16 (x consumed directly by stage-1 GEMM).
// ---------------------------------------------------------------------------
__global__ __launch_bounds__(256)
void prep_kernel(const float* s0, const float* s1, const float* s2,
                 const float* s3, const float* s4, const float* s5,
                 _Float16* d0, _Float16* d1, _Float16* d2,
                 _Float16* d3, _Float16* d4, _Float16* d5)
{
    const int bid = blockIdx.x;
    const int j  = bid >> 6;
    const int bx = bid & 63;
    const float* s = j==0?s0: j==1?s1: j==2?s2: j==3?s3: j==4?s4: s5;
    _Float16*  d = j==0?d0: j==1?d1: j==2?d2: j==3?d3: j==4?d4: d5;
    const int  n = (j==3 || j==4) ? 65536 : 131072;
    const int  i = (bx * 256 + threadIdx.x) * 8;
    if (i < n) {
        f16x8 h;
        #pragma unroll
        for (int k = 0; k < 8; ++k) h[k] = (_Float16)s[i + k];
        *(f16x8*)(d + i) = h;
    }
}

// ---------------------------------------------------------------------------
// Pipelined shared-B MFMA GEMM (R13):
//  * A fragments load DIRECTLY from global (per-lane dwordx4): per tile each
//    wave's 16 A-rows are disjoint, so bytes-from-L2 are identical to LDS
//    staging, weights are L2-hot across the 1024 blocks, and A leaves LDS.
//  * B double-buffered in LDS (2 x 8KB only): true 2-phase pipeline, ONE
//    barrier per K-tile. Issue order per tile: afr loads (oldest; MFMA's
//    vmcnt wait then leaves younger B-prefetch in flight) -> B stage for
//    tile t+1 -> MFMA cluster -> (f32 path: cvt+ds_write) -> barrier.
//  * nA A-tiles (64 rows) share each staged B tile (R12's lever):
//    stage 1: nA=3 = jobs {v,k1,q1}, B reg-staged from f32 x (T14 split)
//    stage 2: nA=2 = two 64-row halves of k2 (u<2) or q2 (u>=2)
//    stage 4: nA=2 = two 64-row halves of the final conv
//  * Block = 256 thr = 4 waves; B tile 64 px; wave = 16 rows x 64 px per A
//    slot = nA*8 MFMA per K-tile. XOR swizzle (byte ^= (row&7)<<4) both sides.
//  * Grid 1024: xcd=bid&7, nb=xcd*32+(jj>>2), u=jj&3 (u fastest -> same-B
//    blocks consecutive on one XCD for L2 reuse).
// mode: 0 = f16 out (p,c);  2 = f32 out (b,c,p)
// ---------------------------------------------------------------------------
struct GJob {
    const _Float16* in;   // (16384, K) f16, or null
    const float*    xf;   // (b,c,p) f32, or null
    const _Float16* w;    // (O, K) f16
    const float* b; const float* g; const float* be; const float* m; const float* v;
    _Float16* oh;
    float*    of;
};

__global__ __launch_bounds__(256)
void gemm_f(GJob J0, GJob J1, GJob J2, int stage, int K, int JO, int mode)
{
    __shared__ _Float16 Bs[2][64 * 64];   // 2 x 8 KB, XOR-swizzled rows

    const int tid  = threadIdx.x;
    const int lane = tid & 63;
    const int w4   = tid >> 6;            // wave 0..3
    const int lr   = lane & 15;
    const int lg   = lane >> 4;

    const int bid = blockIdx.x;           // 1024 blocks
    const int xcd = bid & 7;
    const int jj  = bid >> 3;
    const int nb  = xcd * 32 + (jj >> 2); // pixel chunk 0..255 (64 px each)
    const int u   = jj & 3;

    const int nA = (stage == 1) ? 3 : 2;
    int js0, js1, js2, ob0, ob1, ob2;
    if (stage == 1)      { js0 = 0; js1 = 1; js2 = 2; ob0 = ob1 = ob2 = u * 64; }
    else if (stage == 2) { js0 = js1 = js2 = (u >> 1); ob0 = (u & 1) * 128; ob1 = ob0 + 64; ob2 = ob1; }
    else                 { js0 = js1 = js2 = 0; ob0 = u * 128; ob1 = ob0 + 64; ob2 = ob1; }

#define JSEL(js, f) ((js) == 0 ? J0.f : ((js) == 1 ? J1.f : J2.f))
    const _Float16* w0 = JSEL(js0, w);
    const _Float16* w1 = JSEL(js1, w);
    const _Float16* w2 = JSEL(js2, w);
    const float* b0 = JSEL(js0, b); const float* g0 = JSEL(js0, g);
    const float* be0 = JSEL(js0, be); const float* m0 = JSEL(js0, m); const float* v0 = JSEL(js0, v);
    const float* b1 = JSEL(js1, b); const float* g1 = JSEL(js1, g);
    const float* be1 = JSEL(js1, be); const float* m1 = JSEL(js1, m); const float* v1 = JSEL(js1, v);
    const float* b2 = JSEL(js2, b); const float* g2 = JSEL(js2, g);
    const float* be2 = JSEL(js2, be); const float* m2 = JSEL(js2, m); const float* v2 = JSEL(js2, v);
    _Float16* oh0 = JSEL(js0, oh); float* of0 = JSEL(js0, of);
    _Float16* oh1 = JSEL(js1, oh); float* of1 = JSEL(js1, of);
    _Float16* oh2 = JSEL(js2, oh); float* of2 = JSEL(js2, of);
    const _Float16* bIn = JSEL(js0, in);
    const float*    bXf = JSEL(js0, xf);
#undef JSEL

    // A row pointers: global, per slot (lane owns row w4*16+lr, k-base lg*8)
    const int arow = w4 * 16 + lr;
    const _Float16* aP0 = w0 + (size_t)(ob0 + arow) * K + lg * 8;
    const _Float16* aP1 = w1 + (size_t)(ob1 + arow) * K + lg * 8;
    const _Float16* aP2 = w2 + (size_t)(ob2 + arow) * K + lg * 8;

    // f16-B gld_lds source (cols pre-swizzled, rule #21)
    const int scol = (((lane & 7) ^ (lane >> 3)) << 3);
    const int rowB = w4 * 16 + (lane >> 3);
    const _Float16* bS = bIn ? (bIn + (size_t)(nb * 64 + rowB) * K + scol) : nullptr;

    // f32-direct B staging: thread = (pixel row 0..63, 16-ch quarter)
    const int xrow = tid & 63;
    const int chq  = tid >> 6;                    // 0..3
    const int pgS  = nb * 64 + xrow;
    const float* xbase = bXf ? (bXf + ((size_t)(pgS >> 12) * 512) * HW + (pgS & 4095)) : nullptr;
    const int bxorw = (xrow & 7) << 4;
    const bool f32B = (bXf != nullptr);

    float fr[16];
    auto ISSUE_BX = [&](int rd) {                 // 16 coalesced f32 loads
        const int cb = rd * 64 + chq * 16;
        #pragma unroll
        for (int i2 = 0; i2 < 16; ++i2)
            fr[i2] = xbase[(size_t)(cb + i2) * HW];
    };
    auto WRITE_BX = [&](int buf) {                // cvt + swizzled ds_write
        #pragma unroll
        for (int g4 = 0; g4 < 2; ++g4) {
            f16x8 hv;
            #pragma unroll
            for (int i2 = 0; i2 < 8; ++i2) hv[i2] = (_Float16)fr[g4 * 8 + i2];
            *(f16x8*)((char*)&Bs[buf][0] + xrow * 128 + ((chq * 32 + g4 * 16) ^ bxorw)) = hv;
        }
    };
    auto GLD_B = [&](int rd, int buf) {           // f16 path: 2 x gld_lds/wave
        const int kb = rd * 64;
        gld_lds16(bS + kb,                 (char*)&Bs[buf][0] + w4 * 2048);
        gld_lds16(bS + (size_t)8 * K + kb, (char*)&Bs[buf][0] + w4 * 2048 + 1024);
    };

    f32x4 acc0[4] = {}, acc1[4] = {}, acc2[4] = {};
    const int nr = K >> 6;

    // prologue: stage tile 0 into buf 0
    if (f32B) { ISSUE_BX(0); WRITE_BX(0); }
    else      { GLD_B(0, 0); }
    __syncthreads();

    int cur = 0;
    for (int rd = 0; rd < nr; ++rd) {
        const bool more = (rd + 1 < nr);
        const int kb = rd * 64;

        // A fragments for this tile: issued FIRST (oldest) so the MFMA vmcnt
        // wait does not drain the younger B prefetch below.
        f16x8 a00 = *(const f16x8*)(aP0 + kb);
        f16x8 a01 = *(const f16x8*)(aP0 + kb + 32);
        f16x8 a10 = *(const f16x8*)(aP1 + kb);
        f16x8 a11 = *(const f16x8*)(aP1 + kb + 32);
        f16x8 a20, a21;
        if (nA > 2) {
            a20 = *(const f16x8*)(aP2 + kb);
            a21 = *(const f16x8*)(aP2 + kb + 32);
        }

        if (more) {
            if (f32B) ISSUE_BX(rd + 1);           // regs; written after MFMAs
            else      GLD_B(rd + 1, cur ^ 1);     // async into other buffer
        }

        #pragma unroll
        for (int ks = 0; ks < 2; ++ks) {
            const int colx = (ks * 64 + lg * 16) ^ ((lr & 7) << 4);
            f16x8 bfr[4];
            #pragma unroll
            for (int t = 0; t < 4; ++t)
                bfr[t] = *(const f16x8*)((const char*)&Bs[cur][0] + (t * 16 + lr) * 128 + colx);
            const f16x8 af0 = ks ? a01 : a00;
            const f16x8 af1 = ks ? a11 : a10;
            #pragma unroll
            for (int bj = 0; bj < 4; ++bj)
                acc0[bj] = __builtin_amdgcn_mfma_f32_16x16x32_f16(af0, bfr[bj], acc0[bj], 0, 0, 0);
            #pragma unroll
            for (int bj = 0; bj < 4; ++bj)
                acc1[bj] = __builtin_amdgcn_mfma_f32_16x16x32_f16(af1, bfr[bj], acc1[bj], 0, 0, 0);
            if (nA > 2) {
                const f16x8 af2 = ks ? a21 : a20;
                #pragma unroll
                for (int bj = 0; bj < 4; ++bj)
                    acc2[bj] = __builtin_amdgcn_mfma_f32_16x16x32_f16(af2, bfr[bj], acc2[bj], 0, 0, 0);
            }
        }

        if (f32B && more) WRITE_BX(cur ^ 1);      // vmcnt for fr lands here
        __syncthreads();                          // drains gld_lds/ds_writes
        cur ^= 1;
    }

    // epilogue per slot (BN fold + optional ReLU + store)
#define EPI(accS, obS, bS_, gS, beS, mS, vS, ohS, ofS) do {                      \
        const int o4 = (obS) + w4 * 16 + lg * 4;                                 \
        float sc[4], off[4];                                                     \
        _Pragma("unroll")                                                        \
        for (int r = 0; r < 4; ++r) {                                            \
            const int o = o4 + r;                                                \
            if (gS) { float s = (gS)[o] * rsqrtf((vS)[o] + EPSBN);               \
                      sc[r] = s; off[r] = fmaf((bS_)[o] - (mS)[o], s, (beS)[o]); }\
            else    { sc[r] = 1.f; off[r] = (bS_)[o]; }                          \
        }                                                                        \
        _Pragma("unroll")                                                        \
        for (int bj = 0; bj < 4; ++bj) {                                         \
            const int pg = nb * 64 + bj * 16 + lr;                               \
            float vv[4];                                                         \
            _Pragma("unroll")                                                    \
            for (int r = 0; r < 4; ++r) {                                        \
                float t = fmaf(accS[bj][r], sc[r], off[r]);                      \
                vv[r] = (gS) ? fmaxf(t, 0.f) : t;                                \
            }                                                                    \
            if (mode == 0) {                                                     \
                f16x4 hh;                                                        \
                _Pragma("unroll")                                                \
                for (int r = 0; r < 4; ++r) hh[r] = (_Float16)vv[r];             \
                *(f16x4*)((ohS) + (size_t)pg * JO + o4) = hh;                    \
            } else {                                                             \
                _Pragma("unroll")                                                \
                for (int r = 0; r < 4; ++r)                                      \
                    (ofS)[((size_t)(pg >> 12) * JO + o4 + r) * HW + (pg & 4095)] = vv[r]; \
            }                                                                    \
        }                                                                        \
    } while (0)

    EPI(acc0, ob0, b0, g0, be0, m0, v0, oh0, of0);
    EPI(acc1, ob1, b1, g1, be1, m1, v1, oh1, of1);
    if (nA > 2) EPI(acc2, ob2, b2, g2, be2, m2, v2, oh2, of2);
#undef EPI
}

// ---------------------------------------------------------------------------
// Fused attention: sim + softmax + PV, all buffers (b,p,256) f16.
// Thread = (pixel, 8-ch slot); 32 consecutive lanes read one 512B neighbor
// row coalesced. fdot2 sim partials; shfl_xor reduce over 32 slot-lanes;
// in-register softmax; OOB zeroed via valf (matches zero-padded unfold).
// ---------------------------------------------------------------------------
__global__ __launch_bounds__(256)
void attn_fused(const _Float16* __restrict__ keyT, const _Float16* __restrict__ qryT,
                const _Float16* __restrict__ valT, _Float16* __restrict__ ctxT)
{
    const int tid  = threadIdx.x;
    const int slot = tid & 31;
    const int b    = blockIdx.y;
    const int p    = blockIdx.x * 8 + (tid >> 5);
    const int y    = p >> 6;
    const int xc   = p & 63;

    int   idx[NB];
    float valf[NB];
    #pragma unroll
    for (int n = 0; n < NB; ++n) {
        const int d  = (n < 9) ? 1 : (n < 18 ? 2 : 4);
        const int i  = (n / 3) % 3 - 1;
        const int j  = n % 3 - 1;
        const int yy = y + i * d, xx = xc + j * d;
        const bool ok = ((unsigned)yy < (unsigned)Hh) && ((unsigned)xx < (unsigned)Ww);
        idx[n]  = min(max(yy, 0), Hh - 1) * Ww + min(max(xx, 0), Ww - 1);
        valf[n] = ok ? 1.f : 0.f;
    }

    const size_t base = (size_t)b * HW * 256 + slot * 8;
    const f16x8 q8 = *(const f16x8*)(qryT + base + (size_t)p * 256);

    f16x2 qp[4];
    qp[0] = __builtin_shufflevector(q8, q8, 0, 1);
    qp[1] = __builtin_shufflevector(q8, q8, 2, 3);
    qp[2] = __builtin_shufflevector(q8, q8, 4, 5);
    qp[3] = __builtin_shufflevector(q8, q8, 6, 7);

    float sim[NB];
    #pragma unroll
    for (int n = 0; n < NB; ++n) {
        const f16x8 k8 = *(const f16x8*)(keyT + base + (size_t)idx[n] * 256);
        float s = 0.f;
        s = __builtin_amdgcn_fdot2(__builtin_shufflevector(k8, k8, 0, 1), qp[0], s, false);
        s = __builtin_amdgcn_fdot2(__builtin_shufflevector(k8, k8, 2, 3), qp[1], s, false);
        s = __builtin_amdgcn_fdot2(__builtin_shufflevector(k8, k8, 4, 5), qp[2], s, false);
        s = __builtin_amdgcn_fdot2(__builtin_shufflevector(k8, k8, 6, 7), qp[3], s, false);
        sim[n] = s;
    }

    #pragma unroll
    for (int n = 0; n < NB; ++n) {
        float s = sim[n];
        s += __shfl_xor(s, 1);
        s += __shfl_xor(s, 2);
        s += __shfl_xor(s, 4);
        s += __shfl_xor(s, 8);
        s += __shfl_xor(s, 16);
        sim[n] = s * valf[n];
    }

    float mx = sim[0];
    #pragma unroll
    for (int n = 1; n < NB; ++n) mx = fmaxf(mx, sim[n]);
    float sum = 0.f;
    #pragma unroll
    for (int n = 0; n < NB; ++n) { sim[n] = __expf(sim[n] - mx); sum += sim[n]; }
    const float inv = 1.f / sum;
    #pragma unroll
    for (int n = 0; n < NB; ++n) sim[n] = sim[n] * inv * valf[n];

    float acc[8];
    #pragma unroll
    for (int i = 0; i < 8; ++i) acc[i] = 0.f;
    #pragma unroll
    for (int n = 0; n < NB; ++n) {
        const f16x8 v8 = *(const f16x8*)(valT + base + (size_t)idx[n] * 256);
        const float w = sim[n];
        #pragma unroll
        for (int i = 0; i < 8; ++i) acc[i] = fmaf(w, (float)v8[i], acc[i]);
    }

    f16x8 h;
    #pragma unroll
    for (int i = 0; i < 8; ++i) h[i] = (_Float16)acc[i];
    *(f16x8*)(ctxT + base + (size_t)p * 256) = h;
}

extern "C" void kernel_launch(void* const* d_in, const int* in_sizes, int n_in,
                              void* d_out, int out_size, void* d_ws, size_t ws_size,
                              hipStream_t stream)
{
    (void)in_sizes; (void)n_in; (void)out_size; (void)ws_size;
    const float* x     = (const float*)d_in[0];
    const float* k1_w  = (const float*)d_in[1];
    const float* k1_b  = (const float*)d_in[2];
    const float* k1_g  = (const float*)d_in[3];
    const float* k1_be = (const float*)d_in[4];
    const float* k1_m  = (const float*)d_in[5];
    const float* k1_v  = (const float*)d_in[6];
    const float* k2_w  = (const float*)d_in[7];
    const float* k2_b  = (const float*)d_in[8];
    const float* k2_g  = (const float*)d_in[9];
    const float* k2_be = (const float*)d_in[10];
    const float* k2_m  = (const float*)d_in[11];
    const float* k2_v  = (const float*)d_in[12];
    const float* q1_w  = (const float*)d_in[13];
    const float* q1_b  = (const float*)d_in[14];
    const float* q1_g  = (const float*)d_in[15];
    const float* q1_be = (const float*)d_in[16];
    const float* q1_m  = (const float*)d_in[17];
    const float* q1_v  = (const float*)d_in[18];
    const float* q2_w  = (const float*)d_in[19];
    const float* q2_b  = (const float*)d_in[20];
    const float* q2_g  = (const float*)d_in[21];
    const float* q2_be = (const float*)d_in[22];
    const float* q2_m  = (const float*)d_in[23];
    const float* q2_v  = (const float*)d_in[24];
    const float* v_w   = (const float*)d_in[25];
    const float* v_b   = (const float*)d_in[26];
    const float* w_w   = (const float*)d_in[27];
    const float* w_b   = (const float*)d_in[28];

    _Float16* hw = (_Float16*)d_ws;
    const size_t SH = (size_t)4 * HW * 256;
    _Float16* wv_h  = hw;
    _Float16* wk1_h = wv_h  + 131072;
    _Float16* wq1_h = wk1_h + 131072;
    _Float16* wk2_h = wq1_h + 131072;
    _Float16* wq2_h = wk2_h + 65536;
    _Float16* ww_h  = wq2_h + 65536;
    _Float16* k1T   = ww_h  + 131072;
    _Float16* q1T   = k1T + SH;
    _Float16* valT  = q1T + SH;
    _Float16* ctxT  = valT + SH;
    _Float16* keyPC = ctxT + SH;
    _Float16* qryPC = keyPC + SH;

    prep_kernel<<<384, 256, 0, stream>>>(v_w, k1_w, q1_w, k2_w, q2_w, w_w,
                                         wv_h, wk1_h, wq1_h, wk2_h, wq2_h, ww_h);

    GJob jv  = { nullptr, x, wv_h,  v_b,  nullptr, nullptr, nullptr, nullptr, valT,  nullptr };
    GJob jk1 = { nullptr, x, wk1_h, k1_b, k1_g, k1_be, k1_m, k1_v,            k1T,   nullptr };
    GJob jq1 = { nullptr, x, wq1_h, q1_b, q1_g, q1_be, q1_m, q1_v,            q1T,   nullptr };
    GJob jk2 = { k1T, nullptr, wk2_h, k2_b, k2_g, k2_be, k2_m, k2_v,          keyPC, nullptr };
    GJob jq2 = { q1T, nullptr, wq2_h, q2_b, q2_g, q2_be, q2_m, q2_v,          qryPC, nullptr };
    GJob jw  = { ctxT, nullptr, ww_h, w_b,  nullptr, nullptr, nullptr, nullptr, nullptr, (float*)d_out };

    // stage 1: {v,k1,q1} share staged B (f32 x direct); B dbuf pipeline
    gemm_f<<<1024, 256, 0, stream>>>(jv, jk1, jq1, 1, 512, 256, 0);
    // stage 2: k2 | q2, two 64-row A-tiles share B per block
    gemm_f<<<1024, 256, 0, stream>>>(jk2, jq2, jq2, 2, 256, 256, 0);
    // stage 3: fused sim+softmax+PV -> ctxT (p,c) f16
    attn_fused<<<dim3(512, 4), 256, 0, stream>>>(keyPC, qryPC, valT, ctxT);
    // stage 4: final conv, out f32 (b,c,p) -> d_out
    gemm_f<<<1024, 256, 0, stream>>>(jw, jw, jw, 4, 256, 512, 2);
}

// Round 14
// 85.585 us; speedup vs baseline: 1.3453x; 1.3453x over previous
//
#include <hip/hip_runtime.h>

#define HW   4096
#define Hh   64
#define Ww   64
#define NB   27
#define EPSBN 1e-5f

typedef _Float16 f16x8 __attribute__((ext_vector_type(8)));
typedef _Float16 f16x4 __attribute__((ext_vector_type(4)));
typedef _Float16 f16x2 __attribute__((ext_vector_type(2)));
typedef float    f32x4 __attribute__((ext_vector_type(4)));

// async global->LDS, 16B per lane; LDS dest = wave-uniform base + lane*16
__device__ __forceinline__ void gld_lds16(const void* g, void* l) {
    __builtin_amdgcn_global_load_lds(
        (const __attribute__((address_space(1))) unsigned int*)g,
        (__attribute__((address_space(3))) unsigned int*)l, 16, 0, 0);
}

// ---------------------------------------------------------------------------
// prep: weights f32 -> f16 (x consumed directly by stage-1 GEMM).
// ---------------------------------------------------------------------------
__global__ __launch_bounds__(256)
void prep_kernel(const float* s0, const float* s1, const float* s2,
                 const float* s3, const float* s4, const float* s5,
                 _Float16* d0, _Float16* d1, _Float16* d2,
                 _Float16* d3, _Float16* d4, _Float16* d5)
{
    const int bid = blockIdx.x;
    const int j  = bid >> 6;
    const int bx = bid & 63;
    const float* s = j==0?s0: j==1?s1: j==2?s2: j==3?s3: j==4?s4: s5;
    _Float16*  d = j==0?d0: j==1?d1: j==2?d2: j==3?d3: j==4?d4: d5;
    const int  n = (j==3 || j==4) ? 65536 : 131072;
    const int  i = (bx * 256 + threadIdx.x) * 8;
    if (i < n) {
        f16x8 h;
        #pragma unroll
        for (int k = 0; k < 8; ++k) h[k] = (_Float16)s[i + k];
        *(f16x8*)(d + i) = h;
    }
}

// ---------------------------------------------------------------------------
// R14 GEMM: high-intensity shared-B tile + full double-buffering.
// R13 post-mortem: per-CU L1 port (~64 B/cy) was ~75% busy moving ~41-57KB
// per 240-MFMA-cycle tile -> MfmaUtil pinned at 8-10% regardless of
// occupancy. Fix = raise FLOP/byte: B tile 256 px x 64 k shared by nA
// A-slots (64 rows each) -> ~70 FLOP/B (L1 roofline ~73), and double-buffer
// BOTH operands (LDS 112KB, 1 block/CU) so each tile's staging is issued a
// full tile ahead: ONE barrier per K-tile, no naked drain.
//   stage 1: nA=3 = jobs {v,k1,q1} (same B = x), B reg-staged from f32 x
//            (thread = one px row -> XOR-swizzle write keys span all 8; R12's
//            proven conflict-free pattern)
//   stage 2: nA=2 = two 64-row halves of k2 (u<2) or q2 (u>=2), B via gld_lds
//   stage 4: nA=2 = two 64-row halves of final conv, u = 128-row chunk
// Block 512 thr = 8 waves (wq = 16-row quarter, ph = 128-px half); per wave
// per K-tile: nA x 8 frags x 2 ks = nA*16 MFMA. Grid = 256 = 1 block/CU.
// mode: 0 = f16 out (p,c);  2 = f32 out (b,c,p)
// ---------------------------------------------------------------------------
struct GJob {
    const _Float16* in;   // (16384, K) f16, or null
    const float*    xf;   // (b,c,p) f32, or null
    const _Float16* w;    // (O, K) f16
    const float* b; const float* g; const float* be; const float* m; const float* v;
    _Float16* oh;
    float*    of;
};

__global__ __launch_bounds__(512, 2)
void gemm_f(GJob J0, GJob J1, GJob J2, int stage, int K, int JO, int mode)
{
    __shared__ _Float16 As[2][3][4096];   // 2 buf x 3 slots x 8KB = 48 KB
    __shared__ _Float16 Bs[2][16384];     // 2 buf x 32KB (256 px x 64 k)

    const int tid  = threadIdx.x;
    const int lane = tid & 63;
    const int w8   = tid >> 6;            // wave 0..7
    const int lr   = lane & 15;
    const int lg   = lane >> 4;
    const int wq   = w8 & 3;              // 16-row quarter of each 64-row slot
    const int ph   = w8 >> 2;             // 128-px half of the 256-px tile

    const int bid = blockIdx.x;           // 256 blocks = 1/CU
    const int xcd = bid & 7;
    const int jj  = bid >> 3;             // 0..31
    const int nb  = xcd * 8 + (jj >> 2);  // 256-px chunk 0..63 (XCD-local)
    const int u   = jj & 3;

    const int nA = (stage == 1) ? 3 : 2;
    int js0, js1, js2, ob0, ob1, ob2;
    if (stage == 1)      { js0 = 0; js1 = 1; js2 = 2; ob0 = ob1 = ob2 = u * 64; }
    else if (stage == 2) { js0 = js1 = js2 = (u >> 1); ob0 = (u & 1) * 128; ob1 = ob0 + 64; ob2 = ob1; }
    else                 { js0 = js1 = js2 = 0; ob0 = u * 128; ob1 = ob0 + 64; ob2 = ob1; }

#define JSEL(js, f) ((js) == 0 ? J0.f : ((js) == 1 ? J1.f : J2.f))
    const _Float16* w0 = JSEL(js0, w);
    const _Float16* w1 = JSEL(js1, w);
    const _Float16* w2 = JSEL(js2, w);
    const float* b0 = JSEL(js0, b); const float* g0 = JSEL(js0, g);
    const float* be0 = JSEL(js0, be); const float* m0 = JSEL(js0, m); const float* v0 = JSEL(js0, v);
    const float* b1 = JSEL(js1, b); const float* g1 = JSEL(js1, g);
    const float* be1 = JSEL(js1, be); const float* m1 = JSEL(js1, m); const float* v1 = JSEL(js1, v);
    const float* b2 = JSEL(js2, b); const float* g2 = JSEL(js2, g);
    const float* be2 = JSEL(js2, be); const float* m2 = JSEL(js2, m); const float* v2 = JSEL(js2, v);
    _Float16* oh0 = JSEL(js0, oh); float* of0 = JSEL(js0, of);
    _Float16* oh1 = JSEL(js1, oh); float* of1 = JSEL(js1, of);
    _Float16* oh2 = JSEL(js2, oh); float* of2 = JSEL(js2, of);
    const _Float16* bIn = JSEL(js0, in);
    const float*    bXf = JSEL(js0, xf);
#undef JSEL

    // A staging: wave w8 covers rows w8*8+(lane>>3); cols pre-swizzled (r#21)
    const int scol = (((lane & 7) ^ (lane >> 3)) << 3);
    const int rowA = w8 * 8 + (lane >> 3);
    const _Float16* aS0 = w0 + (size_t)(ob0 + rowA) * K + scol;
    const _Float16* aS1 = w1 + (size_t)(ob1 + rowA) * K + scol;
    const _Float16* aS2 = w2 + (size_t)(ob2 + rowA) * K + scol;

    // B f16 staging: wave w8 covers rows w8*32 + j*8 + (lane>>3), j=0..3
    const int rowB = w8 * 32 + (lane >> 3);
    const _Float16* bS = bIn ? (bIn + (size_t)(nb * 256 + rowB) * K + scol) : nullptr;

    // B f32 staging (stage 1): thread = one px row (tid&255), 32-ch half
    const int px   = tid & 255;
    const int chh  = tid >> 8;                 // 0/1
    const int pgS  = nb * 256 + px;
    const float* xbase = bXf ? (bXf + (size_t)(pgS >> 12) * 512 * HW + (pgS & 4095)) : nullptr;
    const int bxk  = (px & 7) << 4;
    const bool f32B = (bXf != nullptr);

    float fr[32];
    auto ISSUE_BX = [&](int rd) {              // 32 coalesced dword loads
        const int cb = rd * 64 + chh * 32;
        #pragma unroll
        for (int i2 = 0; i2 < 32; ++i2)
            fr[i2] = xbase[(size_t)(cb + i2) * HW];
    };
    auto WRITE_BX = [&](int buf) {             // cvt + swizzled ds_write x4
        #pragma unroll
        for (int g4 = 0; g4 < 4; ++g4) {
            f16x8 hv;
            #pragma unroll
            for (int i2 = 0; i2 < 8; ++i2) hv[i2] = (_Float16)fr[g4 * 8 + i2];
            *(f16x8*)((char*)&Bs[buf][0] + px * 128 + ((chh * 64 + g4 * 16) ^ bxk)) = hv;
        }
    };
    auto STAGE_B16 = [&](int buf, int rd) {    // 4 gld_lds per wave
        const int kb = rd * 64;
        #pragma unroll
        for (int j2 = 0; j2 < 4; ++j2)
            gld_lds16(bS + (size_t)j2 * 8 * K + kb, (char*)&Bs[buf][0] + w8 * 4096 + j2 * 1024);
    };
    auto STAGE_A = [&](int buf, int rd) {      // nA gld_lds per wave
        const int kb = rd * 64;
        gld_lds16(aS0 + kb, (char*)&As[buf][0][0] + w8 * 1024);
        gld_lds16(aS1 + kb, (char*)&As[buf][1][0] + w8 * 1024);
        if (nA > 2) gld_lds16(aS2 + kb, (char*)&As[buf][2][0] + w8 * 1024);
    };

    f32x4 acc0[8] = {}, acc1[8] = {}, acc2[8] = {};
    const int nr = K >> 6;

    // prologue: stage tile 0 into buffer 0
    if (f32B) { ISSUE_BX(0); WRITE_BX(0); }
    else      { STAGE_B16(0, 0); }
    STAGE_A(0, 0);
    __syncthreads();

    int cur = 0;
    for (int rd = 0; rd < nr; ++rd) {
        const bool more = (rd + 1 < nr);
        if (more) {                            // stage NEXT tile first
            STAGE_A(cur ^ 1, rd + 1);
            if (f32B) ISSUE_BX(rd + 1);        // regs; LDS write after MFMAs
            else      STAGE_B16(cur ^ 1, rd + 1);
        }

        #pragma unroll
        for (int ks = 0; ks < 2; ++ks) {
            const int colx = (ks * 64 + lg * 16) ^ ((lr & 7) << 4);
            f16x8 bfr[8];
            #pragma unroll
            for (int t = 0; t < 8; ++t)
                bfr[t] = *(const f16x8*)((const char*)&Bs[cur][0] + (ph * 128 + t * 16 + lr) * 128 + colx);
            const int aoff = (wq * 16 + lr) * 128 + colx;
            const f16x8 af0 = *(const f16x8*)((const char*)&As[cur][0][0] + aoff);
            const f16x8 af1 = *(const f16x8*)((const char*)&As[cur][1][0] + aoff);
            #pragma unroll
            for (int t = 0; t < 8; ++t)
                acc0[t] = __builtin_amdgcn_mfma_f32_16x16x32_f16(af0, bfr[t], acc0[t], 0, 0, 0);
            #pragma unroll
            for (int t = 0; t < 8; ++t)
                acc1[t] = __builtin_amdgcn_mfma_f32_16x16x32_f16(af1, bfr[t], acc1[t], 0, 0, 0);
            if (nA > 2) {
                const f16x8 af2 = *(const f16x8*)((const char*)&As[cur][2][0] + aoff);
                #pragma unroll
                for (int t = 0; t < 8; ++t)
                    acc2[t] = __builtin_amdgcn_mfma_f32_16x16x32_f16(af2, bfr[t], acc2[t], 0, 0, 0);
            }
        }

        if (f32B && more) WRITE_BX(cur ^ 1);   // vmcnt for fr lands here
        __syncthreads();                       // single barrier per tile
        cur ^= 1;
    }

    // epilogue per slot (BN fold + optional ReLU + store)
#define EPI(accS, obS, bS_, gS, beS, mS, vS, ohS, ofS) do {                      \
        const int o4 = (obS) + wq * 16 + lg * 4;                                 \
        float sc[4], off[4];                                                     \
        _Pragma("unroll")                                                        \
        for (int r = 0; r < 4; ++r) {                                            \
            const int o = o4 + r;                                                \
            if (gS) { float s = (gS)[o] * rsqrtf((vS)[o] + EPSBN);               \
                      sc[r] = s; off[r] = fmaf((bS_)[o] - (mS)[o], s, (beS)[o]); }\
            else    { sc[r] = 1.f; off[r] = (bS_)[o]; }                          \
        }                                                                        \
        _Pragma("unroll")                                                        \
        for (int t = 0; t < 8; ++t) {                                            \
            const int pg = nb * 256 + ph * 128 + t * 16 + lr;                    \
            float vv[4];                                                         \
            _Pragma("unroll")                                                    \
            for (int r = 0; r < 4; ++r) {                                        \
                float tv = fmaf(accS[t][r], sc[r], off[r]);                      \
                vv[r] = (gS) ? fmaxf(tv, 0.f) : tv;                              \
            }                                                                    \
            if (mode == 0) {                                                     \
                f16x4 hh;                                                        \
                _Pragma("unroll")                                                \
                for (int r = 0; r < 4; ++r) hh[r] = (_Float16)vv[r];             \
                *(f16x4*)((ohS) + (size_t)pg * JO + o4) = hh;                    \
            } else {                                                             \
                _Pragma("unroll")                                                \
                for (int r = 0; r < 4; ++r)                                      \
                    (ofS)[((size_t)(pg >> 12) * JO + o4 + r) * HW + (pg & 4095)] = vv[r]; \
            }                                                                    \
        }                                                                        \
    } while (0)

    EPI(acc0, ob0, b0, g0, be0, m0, v0, oh0, of0);
    EPI(acc1, ob1, b1, g1, be1, m1, v1, oh1, of1);
    if (nA > 2) EPI(acc2, ob2, b2, g2, be2, m2, v2, oh2, of2);
#undef EPI
}

// ---------------------------------------------------------------------------
// Fused attention: sim + softmax + PV, all buffers (b,p,256) f16.
// Thread = (pixel, 8-ch slot); 32 consecutive lanes read one 512B neighbor
// row coalesced. fdot2 sim partials; shfl_xor reduce over 32 slot-lanes;
// in-register softmax; OOB zeroed via valf (matches zero-padded unfold).
// ---------------------------------------------------------------------------
__global__ __launch_bounds__(256)
void attn_fused(const _Float16* __restrict__ keyT, const _Float16* __restrict__ qryT,
                const _Float16* __restrict__ valT, _Float16* __restrict__ ctxT)
{
    const int tid  = threadIdx.x;
    const int slot = tid & 31;
    const int b    = blockIdx.y;
    const int p    = blockIdx.x * 8 + (tid >> 5);
    const int y    = p >> 6;
    const int xc   = p & 63;

    int   idx[NB];
    float valf[NB];
    #pragma unroll
    for (int n = 0; n < NB; ++n) {
        const int d  = (n < 9) ? 1 : (n < 18 ? 2 : 4);
        const int i  = (n / 3) % 3 - 1;
        const int j  = n % 3 - 1;
        const int yy = y + i * d, xx = xc + j * d;
        const bool ok = ((unsigned)yy < (unsigned)Hh) && ((unsigned)xx < (unsigned)Ww);
        idx[n]  = min(max(yy, 0), Hh - 1) * Ww + min(max(xx, 0), Ww - 1);
        valf[n] = ok ? 1.f : 0.f;
    }

    const size_t base = (size_t)b * HW * 256 + slot * 8;
    const f16x8 q8 = *(const f16x8*)(qryT + base + (size_t)p * 256);

    f16x2 qp[4];
    qp[0] = __builtin_shufflevector(q8, q8, 0, 1);
    qp[1] = __builtin_shufflevector(q8, q8, 2, 3);
    qp[2] = __builtin_shufflevector(q8, q8, 4, 5);
    qp[3] = __builtin_shufflevector(q8, q8, 6, 7);

    float sim[NB];
    #pragma unroll
    for (int n = 0; n < NB; ++n) {
        const f16x8 k8 = *(const f16x8*)(keyT + base + (size_t)idx[n] * 256);
        float s = 0.f;
        s = __builtin_amdgcn_fdot2(__builtin_shufflevector(k8, k8, 0, 1), qp[0], s, false);
        s = __builtin_amdgcn_fdot2(__builtin_shufflevector(k8, k8, 2, 3), qp[1], s, false);
        s = __builtin_amdgcn_fdot2(__builtin_shufflevector(k8, k8, 4, 5), qp[2], s, false);
        s = __builtin_amdgcn_fdot2(__builtin_shufflevector(k8, k8, 6, 7), qp[3], s, false);
        sim[n] = s;
    }

    #pragma unroll
    for (int n = 0; n < NB; ++n) {
        float s = sim[n];
        s += __shfl_xor(s, 1);
        s += __shfl_xor(s, 2);
        s += __shfl_xor(s, 4);
        s += __shfl_xor(s, 8);
        s += __shfl_xor(s, 16);
        sim[n] = s * valf[n];
    }

    float mx = sim[0];
    #pragma unroll
    for (int n = 1; n < NB; ++n) mx = fmaxf(mx, sim[n]);
    float sum = 0.f;
    #pragma unroll
    for (int n = 0; n < NB; ++n) { sim[n] = __expf(sim[n] - mx); sum += sim[n]; }
    const float inv = 1.f / sum;
    #pragma unroll
    for (int n = 0; n < NB; ++n) sim[n] = sim[n] * inv * valf[n];

    float acc[8];
    #pragma unroll
    for (int i = 0; i < 8; ++i) acc[i] = 0.f;
    #pragma unroll
    for (int n = 0; n < NB; ++n) {
        const f16x8 v8 = *(const f16x8*)(valT + base + (size_t)idx[n] * 256);
        const float w = sim[n];
        #pragma unroll
        for (int i = 0; i < 8; ++i) acc[i] = fmaf(w, (float)v8[i], acc[i]);
    }

    f16x8 h;
    #pragma unroll
    for (int i = 0; i < 8; ++i) h[i] = (_Float16)acc[i];
    *(f16x8*)(ctxT + base + (size_t)p * 256) = h;
}

extern "C" void kernel_launch(void* const* d_in, const int* in_sizes, int n_in,
                              void* d_out, int out_size, void* d_ws, size_t ws_size,
                              hipStream_t stream)
{
    (void)in_sizes; (void)n_in; (void)out_size; (void)ws_size;
    const float* x     = (const float*)d_in[0];
    const float* k1_w  = (const float*)d_in[1];
    const float* k1_b  = (const float*)d_in[2];
    const float* k1_g  = (const float*)d_in[3];
    const float* k1_be = (const float*)d_in[4];
    const float* k1_m  = (const float*)d_in[5];
    const float* k1_v  = (const float*)d_in[6];
    const float* k2_w  = (const float*)d_in[7];
    const float* k2_b  = (const float*)d_in[8];
    const float* k2_g  = (const float*)d_in[9];
    const float* k2_be = (const float*)d_in[10];
    const float* k2_m  = (const float*)d_in[11];
    const float* k2_v  = (const float*)d_in[12];
    const float* q1_w  = (const float*)d_in[13];
    const float* q1_b  = (const float*)d_in[14];
    const float* q1_g  = (const float*)d_in[15];
    const float* q1_be = (const float*)d_in[16];
    const float* q1_m  = (const float*)d_in[17];
    const float* q1_v  = (const float*)d_in[18];
    const float* q2_w  = (const float*)d_in[19];
    const float* q2_b  = (const float*)d_in[20];
    const float* q2_g  = (const float*)d_in[21];
    const float* q2_be = (const float*)d_in[22];
    const float* q2_m  = (const float*)d_in[23];
    const float* q2_v  = (const float*)d_in[24];
    const float* v_w   = (const float*)d_in[25];
    const float* v_b   = (const float*)d_in[26];
    const float* w_w   = (const float*)d_in[27];
    const float* w_b   = (const float*)d_in[28];

    _Float16* hw = (_Float16*)d_ws;
    const size_t SH = (size_t)4 * HW * 256;
    _Float16* wv_h  = hw;
    _Float16* wk1_h = wv_h  + 131072;
    _Float16* wq1_h = wk1_h + 131072;
    _Float16* wk2_h = wq1_h + 131072;
    _Float16* wq2_h = wk2_h + 65536;
    _Float16* ww_h  = wq2_h + 65536;
    _Float16* k1T   = ww_h  + 131072;
    _Float16* q1T   = k1T + SH;
    _Float16* valT  = q1T + SH;
    _Float16* ctxT  = valT + SH;
    _Float16* keyPC = ctxT + SH;
    _Float16* qryPC = keyPC + SH;

    prep_kernel<<<384, 256, 0, stream>>>(v_w, k1_w, q1_w, k2_w, q2_w, w_w,
                                         wv_h, wk1_h, wq1_h, wk2_h, wq2_h, ww_h);

    GJob jv  = { nullptr, x, wv_h,  v_b,  nullptr, nullptr, nullptr, nullptr, valT,  nullptr };
    GJob jk1 = { nullptr, x, wk1_h, k1_b, k1_g, k1_be, k1_m, k1_v,            k1T,   nullptr };
    GJob jq1 = { nullptr, x, wq1_h, q1_b, q1_g, q1_be, q1_m, q1_v,            q1T,   nullptr };
    GJob jk2 = { k1T, nullptr, wk2_h, k2_b, k2_g, k2_be, k2_m, k2_v,          keyPC, nullptr };
    GJob jq2 = { q1T, nullptr, wq2_h, q2_b, q2_g, q2_be, q2_m, q2_v,          qryPC, nullptr };
    GJob jw  = { ctxT, nullptr, ww_h, w_b,  nullptr, nullptr, nullptr, nullptr, nullptr, (float*)d_out };

    // stage 1: {v,k1,q1} share one staged B (f32 x); 256 blocks x 512 thr
    gemm_f<<<256, 512, 0, stream>>>(jv, jk1, jq1, 1, 512, 256, 0);
    // stage 2: k2 | q2, two 64-row A-slots share B per block
    gemm_f<<<256, 512, 0, stream>>>(jk2, jq2, jq2, 2, 256, 256, 0);
    // stage 3: fused sim+softmax+PV -> ctxT (p,c) f16
    attn_fused<<<dim3(512, 4), 256, 0, stream>>>(keyPC, qryPC, valT, ctxT);
    // stage 4: final conv, out f32 (b,c,p) -> d_out
    gemm_f<<<256, 512, 0, stream>>>(jw, jw, jw, 4, 256, 512, 2);
}